// Round 10
// baseline (657.368 us; speedup 1.0000x reference)
//
#include <hip/hip_runtime.h>
#include <cstdint>
#include <cstddef>

#define FEATURE_IN 4096
#define FEATURE_OUT 4096
#define RNK 16

typedef __bf16 bf16x8_t __attribute__((ext_vector_type(8)));
typedef __bf16 bf16x4_t __attribute__((ext_vector_type(4)));
typedef float f32x4_t __attribute__((ext_vector_type(4)));

typedef const __attribute__((address_space(1))) bf16x8_t* gb8p;

// ================= prep_all: one dispatch, two roles (FROZEN; measured <124 us) =====
#define FW_KB 128
#define FW_NB 32
#define NFUSE 4096            // (K/FW_KB)*(N/FW_NB) = 32*128
#define NCVTB 2048
#define CVT_THREADS (NCVTB * 256)                   // 524288
#define CVT_CHUNKS 16                               // 8388608 float4s total

__global__ __launch_bounds__(256) void prep_all(const float* __restrict__ x,
                                                uint16_t* __restrict__ xb,
                                                const float* __restrict__ w,
                                                const float* __restrict__ la,
                                                const float* __restrict__ lb,
                                                uint16_t* __restrict__ wf) {
    __shared__ float las[FW_KB * RNK];     // [k][r], 8 KB
    __shared__ float lbs[RNK * FW_NB];     // [r][n], 2 KB

    const int tid = threadIdx.x;

    if (blockIdx.x >= NFUSE) {
        // ---- convert role ----
        const int tg = (blockIdx.x - NFUSE) * 256 + tid;
        const f32x4_t* xp = (const f32x4_t*)x;
        bf16x4_t* op = (bf16x4_t*)xb;
#pragma unroll
        for (int i = 0; i < CVT_CHUNKS; ++i) {
            const int idx = i * CVT_THREADS + tg;
            f32x4_t v = xp[idx];
            bf16x4_t o;
            o[0] = (__bf16)v[0]; o[1] = (__bf16)v[1];
            o[2] = (__bf16)v[2]; o[3] = (__bf16)v[3];
            op[idx] = o;
        }
        return;
    }

    // ---- fuse role ----
    const int bid = blockIdx.x;
    const int kb = (bid & 31) * FW_KB;
    const int nb = (bid >> 5) * FW_NB;

    {
        const float4* src = (const float4*)(la + (size_t)kb * RNK);
        float4* dst = (float4*)las;
        dst[tid] = src[tid];
        dst[tid + 256] = src[tid + 256];
    }
#pragma unroll
    for (int f = tid; f < RNK * FW_NB; f += 256) {
        int r = f >> 5;
        int nl = f & 31;
        lbs[r * FW_NB + nl] = lb[(size_t)r * FEATURE_OUT + nb + nl];
    }
    __syncthreads();

    const int nl = tid >> 3;    // 0..31
    const int kq = tid & 7;     // 0..7, each covers 16 k

    f32x4_t bcol[4];
#pragma unroll
    for (int r4 = 0; r4 < 4; ++r4) {
        f32x4_t v;
#pragma unroll
        for (int j = 0; j < 4; ++j) v[j] = lbs[(r4 * 4 + j) * FW_NB + nl];
        bcol[r4] = v;
    }

    const f32x4_t* las4 = (const f32x4_t*)las;   // index k*4 + r4
    const float* wrow = w + (size_t)(nb + nl) * FEATURE_IN + kb + kq * 16;
    uint16_t* wfrow = wf + (size_t)(nb + nl) * FEATURE_IN + kb + kq * 16;

#pragma unroll
    for (int h = 0; h < 2; ++h) {          // two groups of 8 k
        float4 wv0 = ((const float4*)wrow)[h * 2 + 0];
        float4 wv1 = ((const float4*)wrow)[h * 2 + 1];
        float wfv[8] = {wv0.x, wv0.y, wv0.z, wv0.w, wv1.x, wv1.y, wv1.z, wv1.w};
        bf16x8_t o;
#pragma unroll
        for (int j = 0; j < 8; ++j) {
            const int k = kq * 16 + h * 8 + j;
            float s = 0.f;
#pragma unroll
            for (int rr = 0; rr < 4; ++rr) {
                const int r4 = (rr + kq) & 3;
                f32x4_t av = las4[k * 4 + r4];
                f32x4_t bv = bcol[r4];
                s += av[0] * bv[0] + av[1] * bv[1] + av[2] * bv[2] + av[3] * bv[3];
            }
            o[j] = (__bf16)(wfv[j] + 2.f * s);
        }
        ((bf16x8_t*)wfrow)[h] = o;
    }
}

// ========== GEMM: 256x256, BK=32, A via LDS (4x16KB bufs), B DIRECT from L2 =========
// r9 post-mortem: occupancy is register-capped at 2 waves/SIMD (acc 128 + arch 128
// = 256 regs); the binding resource is LDS bandwidth (57 B/cyc achieved of ~85).
// Fix: remove B from LDS entirely.  B-frags load straight from wf into bqr[parity]
// (per row, lanes q=0..3 cover 64B contiguous -> clean L2 lines), issued ONE FULL
// TILE ahead (~2000cyc cover).  LDS now carries A only: 80KB/tile (was 128KB).
// n-grouped XCD swizzle: each XCD owns 2 n-panels (4MB == its L2) x all 32 m-panels,
// so B reads are L2-hits; A streams via L3 (read 2x per XCD, L3-hot).
// Per tile t (buf B=t&3, parity S=t&1), ONE vmcnt/tile:
//   X: READ_AFY(B)[4 ds] | STAGE_A(t+3)[2 gll] | BQLOAD(t+1 -> bqr[S^1])[4 glb];
//      VMCNT(6) (keeps {A(t+3),bq(t+1)}; retires bq(t) for MFMA-X and A(t+1) for
//      the barrier publish); MFMA16X(S); BAR
//   Y: READ_R0A(t+1)[4 ds] | MFMA16Y(S); BAR
// WAR: stage into buf(t+3)&3 = buf(t-1)&3, whose afy-read was 2 barriers earlier.
// LDS placement row*64 + (((row>>1)+q)&3)*16: measured SQ_LDS_BANK_CONFLICT == 0.
#define BM 256
#define BN 256
#define BK 32
#define NT (FEATURE_IN / BK)   // 128 K-tiles

#define ABUF(b) ((b) * 16384)

#define MFMA16X(S) do { _Pragma("unroll")                                                \
    for (int _mi = 0; _mi < 4; ++_mi) { _Pragma("unroll")                                \
        for (int _ni = 0; _ni < 4; ++_ni)                                                \
            acc[_mi][_ni] = __builtin_amdgcn_mfma_f32_16x16x32_bf16(                     \
                afx[_mi], bqr[S][_ni], acc[_mi][_ni], 0, 0, 0); } } while (0)

#define MFMA16Y(S) do { _Pragma("unroll")                                                \
    for (int _mi = 0; _mi < 4; ++_mi) { _Pragma("unroll")                                \
        for (int _ni = 0; _ni < 4; ++_ni)                                                \
            acc[4 + _mi][_ni] = __builtin_amdgcn_mfma_f32_16x16x32_bf16(                 \
                afy[_mi], bqr[S][_ni], acc[4 + _mi][_ni], 0, 0, 0); } } while (0)

#define READ_AFY(b) do { _Pragma("unroll")                                               \
    for (int _mi = 0; _mi < 4; ++_mi)                                                    \
        afy[_mi] = *(const bf16x8_t*)(lds + ABUF(b) + aoff[4 + _mi]); } while (0)

#define READ_R0A(b) do { _Pragma("unroll")                                               \
    for (int _mi = 0; _mi < 4; ++_mi)                                                    \
        afx[_mi] = *(const bf16x8_t*)(lds + ABUF(b) + aoff[_mi]); } while (0)

#define GLL(SRC, DSTOFF)                                                                 \
    __builtin_amdgcn_global_load_lds(                                                    \
        (const __attribute__((address_space(1))) void*)(SRC),                            \
        (__attribute__((address_space(3))) void*)(lds + (DSTOFF) + wv * 1024), 16, 0, 0)

#define STAGE_A(b) do { GLL(pA0, ABUF(b)); GLL(pA1, ABUF(b) + 8192);                     \
                        pA0 += BK; pA1 += BK; } while (0)

#define BQLOAD(SN) do {                                                                  \
    bqr[SN][0] = *(gb8p)(pBq0); pBq0 += BK;                                              \
    bqr[SN][1] = *(gb8p)(pBq1); pBq1 += BK;                                              \
    bqr[SN][2] = *(gb8p)(pBq2); pBq2 += BK;                                              \
    bqr[SN][3] = *(gb8p)(pBq3); pBq3 += BK; } while (0)

#define PBAR() __builtin_amdgcn_s_barrier()
#define PRIO1 __builtin_amdgcn_s_setprio(1)
#define PRIO0 __builtin_amdgcn_s_setprio(0)
#define VMCNT(n) asm volatile("s_waitcnt vmcnt(" #n ")" ::: "memory")
#define SCHEDB() __builtin_amdgcn_sched_barrier(0)

// Tile t in buf B (parity S), staging A(t+3) and loading bq(t+1).
#define BODY(B, S)                                                                       \
    READ_AFY(B);                                                                         \
    STAGE_A((B + 3) & 3);                                                                \
    BQLOAD((S) ^ 1);                                                                     \
    VMCNT(6);                                                                            \
    SCHEDB();                                                                            \
    PRIO1; MFMA16X(S); PRIO0;                                                            \
    PBAR();                                                                              \
    READ_R0A((B + 1) & 3);                                                               \
    SCHEDB();                                                                            \
    PRIO1; MFMA16Y(S); PRIO0;                                                            \
    PBAR();

// Tail: no A-staging; BQ optional; NWAIT counted per drain ledger.
#define TAILB(B, S, NWAIT)                                                               \
    READ_AFY(B);                                                                         \
    BQLOAD((S) ^ 1);                                                                     \
    VMCNT(NWAIT);                                                                        \
    SCHEDB();                                                                            \
    PRIO1; MFMA16X(S); PRIO0;                                                            \
    PBAR();                                                                              \
    READ_R0A((B + 1) & 3);                                                               \
    SCHEDB();                                                                            \
    PRIO1; MFMA16Y(S); PRIO0;                                                            \
    PBAR();

__global__ __launch_bounds__(512, 2) void gemm256(const uint16_t* __restrict__ Au,
                                                  const uint16_t* __restrict__ Bu,
                                                  const float* __restrict__ bias,
                                                  float* __restrict__ C,
                                                  int M, int N, int K) {
    __shared__ __align__(16) char lds[65536];   // 4 bufs x A 16KB

    const __bf16* A = (const __bf16*)Au;
    const __bf16* B = (const __bf16*)Bu;

    const int tid  = threadIdx.x;
    const int wv   = tid >> 6;          // 0..7
    const int lane = tid & 63;
    const int waveM = wv >> 2;          // 0..1
    const int waveN = wv & 3;           // 0..3
    const int l15 = lane & 15;
    const int q   = lane >> 4;          // fragment k-chunk 0..3

    // n-grouped XCD swizzle: XCD (bidlin&7) owns bx in {2x, 2x+1} (4MB of wf = its
    // L2) x all 32 m-panels.  Bijective: 3+1+5 bits.
    const int nbx = N / BN;             // 16
    const int bidlin = blockIdx.y * nbx + blockIdx.x;
    const int bx = (bidlin & 7) * 2 + ((bidlin >> 3) & 1);
    const int by = bidlin >> 4;
    const int m0 = by * BM;
    const int n0 = bx * BN;

    // A staging source mapping (chunk c -> row c>>2, phys slot c&3)
    const int srow = tid >> 2;
    const int sq   = ((tid & 3) - (srow >> 1)) & 3;
    const __bf16* pA0 = A + (size_t)(m0 + srow) * K + sq * 8;
    const __bf16* pA1 = pA0 + (size_t)128 * K;

    // B direct-load pointers: lane (l15, q), row n0 + waveN*64 + ni*16 + l15
    const __bf16* pBq0 = B + (size_t)(n0 + waveN * 64 + 0  + l15) * K + q * 8;
    const __bf16* pBq1 = B + (size_t)(n0 + waveN * 64 + 16 + l15) * K + q * 8;
    const __bf16* pBq2 = B + (size_t)(n0 + waveN * 64 + 32 + l15) * K + q * 8;
    const __bf16* pBq3 = B + (size_t)(n0 + waveN * 64 + 48 + l15) * K + q * 8;

    // per-thread A fragment LDS byte offsets (within a 16 KB tile block)
    int aoff[8];
#pragma unroll
    for (int mi = 0; mi < 8; ++mi) {
        int row = waveM * 128 + mi * 16 + l15;
        aoff[mi] = row * 64 + (((row >> 1) + q) & 3) * 16;
    }

    f32x4_t acc[8][4];
#pragma unroll
    for (int mi = 0; mi < 8; ++mi)
#pragma unroll
        for (int ni = 0; ni < 4; ++ni)
            acc[mi][ni] = (f32x4_t)0.f;

    // afx/afy single-set (consumed then rewritten, WAR-safe); bqr double by parity
    bf16x8_t afx[4], afy[4], bqr[2][4];

    // ---- prologue: stage A tiles 0,1,2; load bq(0) into bqr[0] ----
    STAGE_A(0);
    STAGE_A(1);
    STAGE_A(2);
    BQLOAD(0);               // bq(0)
    VMCNT(8);                // retire A(0)'s 2 gll; keep {A1,A2,bq0}
    PBAR();                  // publish buf0
    READ_R0A(0);             // prime afx with tile 0

    // ---- main: t = 0..124 (stage A 3..127, bq 1..125) ----
#pragma unroll 1
    for (int i = 0; i < 31; ++i) {
        BODY(0, 0)
        BODY(1, 1)
        BODY(2, 0)
        BODY(3, 1)
    }
    BODY(0, 0)               // t=124

    // ---- drain: t=125 (buf1,S1,bq126,v4), t=126 (buf2,S0,bq127,v4), t=127 ----
    TAILB(1, 1, 4)
    TAILB(2, 0, 4)
    READ_AFY(3);
    VMCNT(0);
    SCHEDB();
    PRIO1; MFMA16X(1); PRIO0;
    PRIO1; MFMA16Y(1); PRIO0;

    // ---- C write: D layout col=lane&15, row=q*4+j ----
#pragma unroll
    for (int ni = 0; ni < 4; ++ni) {
        const int col = n0 + waveN * 64 + ni * 16 + l15;
        const float bv = bias[col];
#pragma unroll
        for (int mi = 0; mi < 8; ++mi) {
            const int row = m0 + waveM * 128 + mi * 16 + q * 4;
            float* op = C + (size_t)row * N + col;
#pragma unroll
            for (int j = 0; j < 4; ++j)
                op[(size_t)j * N] = acc[mi][ni][j] + bv;
        }
    }
}

extern "C" void kernel_launch(void* const* d_in, const int* in_sizes, int n_in,
                              void* d_out, int out_size, void* d_ws, size_t ws_size,
                              hipStream_t stream) {
    const float* x  = (const float*)d_in[0];   // [4,2048,4096]
    const float* w  = (const float*)d_in[1];   // [4096,4096]  (out,in)
    const float* b  = (const float*)d_in[2];   // [4096]
    const float* la = (const float*)d_in[3];   // [4096,16]
    const float* lb = (const float*)d_in[4];   // [16,4096]
    float* out = (float*)d_out;

    const int M = in_sizes[0] / FEATURE_IN;    // 8192
    const int K = FEATURE_IN;
    const int N = FEATURE_OUT;

    uint16_t* xb = (uint16_t*)d_ws;                                  // M*K bf16 = 64 MiB
    uint16_t* wf = (uint16_t*)((char*)d_ws + (size_t)M * K * 2);     // N*K bf16 = 32 MiB

    // 1) prep: x->bf16 + LoRA-folded W->bf16 (single dispatch, both roles)
    prep_all<<<NFUSE + NCVTB, 256, 0, stream>>>(x, xb, w, la, lb, wf);

    // 2) GEMM + bias: 256x256, BK=32, A-only LDS (64KB), B direct from L2
    {
        dim3 grid(N / BN, M / BM);   // (16, 32)
        gemm256<<<grid, 512, 0, stream>>>(xb, wf, b, out, M, N, K);
    }
}

// Round 11
// 514.731 us; speedup vs baseline: 1.2771x; 1.2771x over previous
//
#include <hip/hip_runtime.h>
#include <cstdint>
#include <cstddef>

#define FEATURE_IN 4096
#define FEATURE_OUT 4096
#define RNK 16

typedef __bf16 bf16x8_t __attribute__((ext_vector_type(8)));
typedef __bf16 bf16x4_t __attribute__((ext_vector_type(4)));
typedef float f32x4_t __attribute__((ext_vector_type(4)));

// ================= prep_all: one dispatch, two roles (measured <124 us) =============
// blocks [0, NFUSE)          : Wf[n,k] = bf16(W[n,k] + 2*sum_r A[k,r]*B[r,n])
// blocks [NFUSE, NFUSE+NCVTB): x fp32 -> bf16 (grid-stride, coalesced)
#define FW_KB 128
#define FW_NB 32
#define NFUSE 4096            // (K/FW_KB)*(N/FW_NB) = 32*128
#define NCVTB 2048
#define CVT_THREADS (NCVTB * 256)                   // 524288
#define CVT_CHUNKS 16                               // 8388608 float4s total

__global__ __launch_bounds__(256) void prep_all(const float* __restrict__ x,
                                                uint16_t* __restrict__ xb,
                                                const float* __restrict__ w,
                                                const float* __restrict__ la,
                                                const float* __restrict__ lb,
                                                uint16_t* __restrict__ wf) {
    __shared__ float las[FW_KB * RNK];     // [k][r], 8 KB
    __shared__ float lbs[RNK * FW_NB];     // [r][n], 2 KB

    const int tid = threadIdx.x;

    if (blockIdx.x >= NFUSE) {
        // ---- convert role ----
        const int tg = (blockIdx.x - NFUSE) * 256 + tid;
        const f32x4_t* xp = (const f32x4_t*)x;
        bf16x4_t* op = (bf16x4_t*)xb;
#pragma unroll
        for (int i = 0; i < CVT_CHUNKS; ++i) {
            const int idx = i * CVT_THREADS + tg;
            f32x4_t v = xp[idx];
            bf16x4_t o;
            o[0] = (__bf16)v[0]; o[1] = (__bf16)v[1];
            o[2] = (__bf16)v[2]; o[3] = (__bf16)v[3];
            op[idx] = o;
        }
        return;
    }

    // ---- fuse role ----
    const int bid = blockIdx.x;
    const int kb = (bid & 31) * FW_KB;
    const int nb = (bid >> 5) * FW_NB;

    {
        const float4* src = (const float4*)(la + (size_t)kb * RNK);
        float4* dst = (float4*)las;
        dst[tid] = src[tid];
        dst[tid + 256] = src[tid + 256];
    }
#pragma unroll
    for (int f = tid; f < RNK * FW_NB; f += 256) {
        int r = f >> 5;
        int nl = f & 31;
        lbs[r * FW_NB + nl] = lb[(size_t)r * FEATURE_OUT + nb + nl];
    }
    __syncthreads();

    const int nl = tid >> 3;    // 0..31
    const int kq = tid & 7;     // 0..7, each covers 16 k

    f32x4_t bcol[4];
#pragma unroll
    for (int r4 = 0; r4 < 4; ++r4) {
        f32x4_t v;
#pragma unroll
        for (int j = 0; j < 4; ++j) v[j] = lbs[(r4 * 4 + j) * FW_NB + nl];
        bcol[r4] = v;
    }

    const f32x4_t* las4 = (const f32x4_t*)las;   // index k*4 + r4
    const float* wrow = w + (size_t)(nb + nl) * FEATURE_IN + kb + kq * 16;
    uint16_t* wfrow = wf + (size_t)(nb + nl) * FEATURE_IN + kb + kq * 16;

#pragma unroll
    for (int h = 0; h < 2; ++h) {          // two groups of 8 k
        float4 wv0 = ((const float4*)wrow)[h * 2 + 0];
        float4 wv1 = ((const float4*)wrow)[h * 2 + 1];
        float wfv[8] = {wv0.x, wv0.y, wv0.z, wv0.w, wv1.x, wv1.y, wv1.z, wv1.w};
        bf16x8_t o;
#pragma unroll
        for (int j = 0; j < 8; ++j) {
            const int k = kq * 16 + h * 8 + j;
            float s = 0.f;
#pragma unroll
            for (int rr = 0; rr < 4; ++rr) {
                const int r4 = (rr + kq) & 3;
                f32x4_t av = las4[k * 4 + r4];
                f32x4_t bv = bcol[r4];
                s += av[0] * bv[0] + av[1] * bv[1] + av[2] * bv[2] + av[3] * bv[3];
            }
            o[j] = (__bf16)(wfv[j] + 2.f * s);
        }
        ((bf16x8_t*)wfrow)[h] = o;
    }
}

// ====== GEMM: 256x256, BK=32, 4-buffer stage-3-ahead, reg-pipelined (BEST, r4) ======
// Session-best schedule: 239.5 us, MfmaUtil 53%, SQ_LDS_BANK_CONFLICT = 0.
// Per tile t (buf CUR=t&3, parity S=t&1):
//   X: READ_AFY(t)[4 ds] || STAGE_A(t+3)[2 gll] || MFMA-X(S);  VMCNT(6); BAR
//   Y: READ_R0(t+1)[8 ds] || STAGE_B(t+3)[2 gll] || MFMA-Y(S); BAR
// All fragment reads are one phase ahead of their consuming MFMA; VMCNT(6) retires
// exactly tile t+1's 4 loads (t+2/t+3 stay in flight).  Constraints measured this
// session: occupancy register-pinned at 2 waves/SIMD (acc 128 + arch 128 = 256);
// B-direct-from-L2 and fp32-W-streaming both regress; vmcnt depth and barrier count
// variations are null.
#define BM 256
#define BN 256
#define BK 32
#define NT (FEATURE_IN / BK)   // 128 K-tiles

#define ABUF(b) ((b) * 32768)
#define BBUF(b) ((b) * 32768 + 16384)

#define MFMA16X(S) do { _Pragma("unroll")                                                \
    for (int _mi = 0; _mi < 4; ++_mi) { _Pragma("unroll")                                \
        for (int _ni = 0; _ni < 4; ++_ni)                                                \
            acc[_mi][_ni] = __builtin_amdgcn_mfma_f32_16x16x32_bf16(                     \
                afx[S][_mi], bqr[S][_ni], acc[_mi][_ni], 0, 0, 0); } } while (0)

#define MFMA16Y(S) do { _Pragma("unroll")                                                \
    for (int _mi = 0; _mi < 4; ++_mi) { _Pragma("unroll")                                \
        for (int _ni = 0; _ni < 4; ++_ni)                                                \
            acc[4 + _mi][_ni] = __builtin_amdgcn_mfma_f32_16x16x32_bf16(                 \
                afy[_mi], bqr[S][_ni], acc[4 + _mi][_ni], 0, 0, 0); } } while (0)

#define READ_AFY(b) do { _Pragma("unroll")                                               \
    for (int _mi = 0; _mi < 4; ++_mi)                                                    \
        afy[_mi] = *(const bf16x8_t*)(lds + ABUF(b) + aoff[4 + _mi]); } while (0)

#define READ_R0(b, SN) do { _Pragma("unroll")                                            \
    for (int _mi = 0; _mi < 4; ++_mi)                                                    \
        afx[SN][_mi] = *(const bf16x8_t*)(lds + ABUF(b) + aoff[_mi]);                    \
    _Pragma("unroll")                                                                    \
    for (int _ni = 0; _ni < 4; ++_ni)                                                    \
        bqr[SN][_ni] = *(const bf16x8_t*)(lds + BBUF(b) + boff[_ni]); } while (0)

#define GLL(SRC, DSTOFF)                                                                 \
    __builtin_amdgcn_global_load_lds(                                                    \
        (const __attribute__((address_space(1))) void*)(SRC),                            \
        (__attribute__((address_space(3))) void*)(lds + (DSTOFF) + wv * 1024), 16, 0, 0)

#define STAGE_A(b) do { GLL(pA0, ABUF(b)); GLL(pA1, ABUF(b) + 8192);                     \
                        pA0 += BK; pA1 += BK; } while (0)
#define STAGE_B(b) do { GLL(pB0, BBUF(b)); GLL(pB1, BBUF(b) + 8192);                     \
                        pB0 += BK; pB1 += BK; } while (0)

#define PBAR() __builtin_amdgcn_s_barrier()
#define PRIO1 __builtin_amdgcn_s_setprio(1)
#define PRIO0 __builtin_amdgcn_s_setprio(0)
#define VMCNT(n) asm volatile("s_waitcnt vmcnt(" #n ")" ::: "memory")
#define SCHEDB() __builtin_amdgcn_sched_barrier(0)

// Tile t in buf CUR (parity set S), staging tile t+3 into buf NXT.
#define TILE_BODY(CUR, NXT, S, SN)                                                       \
    READ_AFY(CUR);                                                                       \
    STAGE_A(NXT);                                                                        \
    SCHEDB();                                                                            \
    PRIO1; MFMA16X(S); PRIO0;                                                            \
    VMCNT(6);                                                                            \
    PBAR();                                                                              \
    READ_R0((CUR + 1) & 3, SN);                                                          \
    STAGE_B(NXT);                                                                        \
    SCHEDB();                                                                            \
    PRIO1; MFMA16Y(S); PRIO0;                                                            \
    PBAR();

// Tail tile (no staging): NWAIT counted to retire exactly tile t+1's loads.
#define TAIL_BODY(CUR, S, SN, NWAIT)                                                     \
    READ_AFY(CUR);                                                                       \
    SCHEDB();                                                                            \
    PRIO1; MFMA16X(S); PRIO0;                                                            \
    VMCNT(NWAIT);                                                                        \
    PBAR();                                                                              \
    READ_R0((CUR + 1) & 3, SN);                                                          \
    SCHEDB();                                                                            \
    PRIO1; MFMA16Y(S); PRIO0;                                                            \
    PBAR();

__global__ __launch_bounds__(512, 2) void gemm256(const uint16_t* __restrict__ Au,
                                                  const uint16_t* __restrict__ Bu,
                                                  const float* __restrict__ bias,
                                                  float* __restrict__ C,
                                                  int M, int N, int K) {
    __shared__ __align__(16) char lds[131072];   // 4 bufs x (A 16K | B 16K)

    const __bf16* A = (const __bf16*)Au;
    const __bf16* B = (const __bf16*)Bu;

    const int tid  = threadIdx.x;
    const int wv   = tid >> 6;          // 0..7
    const int lane = tid & 63;
    const int waveM = wv >> 2;          // 0..1
    const int waveN = wv & 3;           // 0..3
    const int l15 = lane & 15;
    const int q   = lane >> 4;          // fragment k-chunk 0..3

    // T1: bijective XCD-chunk swizzle (nwg=512, 512%8==0)
    const int nbx = N / BN;
    const int nwg = nbx * (M / BM);
    const int bidlin = blockIdx.y * nbx + blockIdx.x;
    const int swz = (bidlin & 7) * (nwg >> 3) + (bidlin >> 3);
    const int by = swz / nbx;
    const int bx = swz - by * nbx;
    const int m0 = by * BM;
    const int n0 = bx * BN;

    // staging source mapping (chunk c -> row c>>2, phys slot c&3)
    const int srow = tid >> 2;
    const int sq   = ((tid & 3) - (srow >> 1)) & 3;
    const __bf16* pA0 = A + (size_t)(m0 + srow) * K + sq * 8;
    const __bf16* pA1 = pA0 + (size_t)128 * K;
    const __bf16* pB0 = B + (size_t)(n0 + srow) * K + sq * 8;
    const __bf16* pB1 = pB0 + (size_t)128 * K;

    // per-thread fragment LDS byte offsets (within a 16 KB tile block)
    int aoff[8], boff[4];
#pragma unroll
    for (int mi = 0; mi < 8; ++mi) {
        int row = waveM * 128 + mi * 16 + l15;
        aoff[mi] = row * 64 + (((row >> 1) + q) & 3) * 16;
    }
#pragma unroll
    for (int ni = 0; ni < 4; ++ni) {
        int row = waveN * 64 + ni * 16 + l15;
        boff[ni] = row * 64 + (((row >> 1) + q) & 3) * 16;
    }

    f32x4_t acc[8][4];
#pragma unroll
    for (int mi = 0; mi < 8; ++mi)
#pragma unroll
        for (int ni = 0; ni < 4; ++ni)
            acc[mi][ni] = (f32x4_t)0.f;

    // fragment register sets: afx/bqr double-buffered by tile parity, afy single
    bf16x8_t afx[2][4], afy[4], bqr[2][4];

    // ---- prologue: stage tiles 0,1,2 (12 loads/wave); publish buf0; prime R0(0) ----
    STAGE_A(0); STAGE_B(0);
    STAGE_A(1); STAGE_B(1);
    STAGE_A(2); STAGE_B(2);
    VMCNT(8);   // retire tile 0's 4 loads
    PBAR();
    READ_R0(0, 0);   // prime set0 with tile 0's fragments

    // ---- main: t=0..123 (stage tiles 3..126), parity = t&1 ----
#pragma unroll 1
    for (int i = 0; i < 31; ++i) {
        TILE_BODY(0, 3, 0, 1)
        TILE_BODY(1, 0, 1, 0)
        TILE_BODY(2, 1, 0, 1)
        TILE_BODY(3, 2, 1, 0)
    }
    // t=124 (buf0, set0): stages tile 127 into buf3
    TILE_BODY(0, 3, 0, 1)

    // ---- drain: t=125 (buf1,set1), t=126 (buf2,set0) ----
    TAIL_BODY(1, 1, 0, 4)    // VMCNT(4): retires tile 126's pair
    TAIL_BODY(2, 0, 1, 0)    // VMCNT(0): retires tile 127's pair
    // t=127 (buf3, set1)
    READ_AFY(3);
    SCHEDB();
    PRIO1; MFMA16X(1); PRIO0;
    PRIO1; MFMA16Y(1); PRIO0;

    // ---- C write: D layout col=lane&15, row=q*4+j ----
#pragma unroll
    for (int ni = 0; ni < 4; ++ni) {
        const int col = n0 + waveN * 64 + ni * 16 + l15;
        const float bv = bias[col];
#pragma unroll
        for (int mi = 0; mi < 8; ++mi) {
            const int row = m0 + waveM * 128 + mi * 16 + q * 4;
            float* op = C + (size_t)row * N + col;
#pragma unroll
            for (int j = 0; j < 4; ++j)
                op[(size_t)j * N] = acc[mi][ni][j] + bv;
        }
    }
}

extern "C" void kernel_launch(void* const* d_in, const int* in_sizes, int n_in,
                              void* d_out, int out_size, void* d_ws, size_t ws_size,
                              hipStream_t stream) {
    const float* x  = (const float*)d_in[0];   // [4,2048,4096]
    const float* w  = (const float*)d_in[1];   // [4096,4096]  (out,in)
    const float* b  = (const float*)d_in[2];   // [4096]
    const float* la = (const float*)d_in[3];   // [4096,16]
    const float* lb = (const float*)d_in[4];   // [16,4096]
    float* out = (float*)d_out;

    const int M = in_sizes[0] / FEATURE_IN;    // 8192
    const int K = FEATURE_IN;
    const int N = FEATURE_OUT;

    uint16_t* xb = (uint16_t*)d_ws;                                  // M*K bf16 = 64 MiB
    uint16_t* wf = (uint16_t*)((char*)d_ws + (size_t)M * K * 2);     // N*K bf16 = 32 MiB

    // 1) prep: x->bf16 + LoRA-folded W->bf16 (single dispatch, both roles)
    prep_all<<<NFUSE + NCVTB, 256, 0, stream>>>(x, xb, w, la, lb, wf);

    // 2) GEMM + bias: 256x256, BK=32, 4-buffer, reg-pipelined (session best)
    {
        dim3 grid(N / BN, M / BM);   // (16, 32)
        gemm256<<<grid, 512, 0, stream>>>(xb, wf, b, out, M, N, K);
    }
}

// Round 12
// 504.938 us; speedup vs baseline: 1.3019x; 1.0194x over previous
//
#include <hip/hip_runtime.h>
#include <cstdint>
#include <cstddef>

#define FEATURE_IN 4096
#define FEATURE_OUT 4096
#define RNK 16

typedef __bf16 bf16x8_t __attribute__((ext_vector_type(8)));
typedef __bf16 bf16x4_t __attribute__((ext_vector_type(4)));
typedef float f32x4_t __attribute__((ext_vector_type(4)));

// ================= prep_all: one dispatch, two roles (FROZEN; measured <124 us) =====
#define FW_KB 128
#define FW_NB 32
#define NFUSE 4096            // (K/FW_KB)*(N/FW_NB) = 32*128
#define NCVTB 2048
#define CVT_THREADS (NCVTB * 256)                   // 524288
#define CVT_CHUNKS 16                               // 8388608 float4s total

__global__ __launch_bounds__(256) void prep_all(const float* __restrict__ x,
                                                uint16_t* __restrict__ xb,
                                                const float* __restrict__ w,
                                                const float* __restrict__ la,
                                                const float* __restrict__ lb,
                                                uint16_t* __restrict__ wf) {
    __shared__ float las[FW_KB * RNK];     // [k][r], 8 KB
    __shared__ float lbs[RNK * FW_NB];     // [r][n], 2 KB

    const int tid = threadIdx.x;

    if (blockIdx.x >= NFUSE) {
        // ---- convert role ----
        const int tg = (blockIdx.x - NFUSE) * 256 + tid;
        const f32x4_t* xp = (const f32x4_t*)x;
        bf16x4_t* op = (bf16x4_t*)xb;
#pragma unroll
        for (int i = 0; i < CVT_CHUNKS; ++i) {
            const int idx = i * CVT_THREADS + tg;
            f32x4_t v = xp[idx];
            bf16x4_t o;
            o[0] = (__bf16)v[0]; o[1] = (__bf16)v[1];
            o[2] = (__bf16)v[2]; o[3] = (__bf16)v[3];
            op[idx] = o;
        }
        return;
    }

    // ---- fuse role ----
    const int bid = blockIdx.x;
    const int kb = (bid & 31) * FW_KB;
    const int nb = (bid >> 5) * FW_NB;

    {
        const float4* src = (const float4*)(la + (size_t)kb * RNK);
        float4* dst = (float4*)las;
        dst[tid] = src[tid];
        dst[tid + 256] = src[tid + 256];
    }
#pragma unroll
    for (int f = tid; f < RNK * FW_NB; f += 256) {
        int r = f >> 5;
        int nl = f & 31;
        lbs[r * FW_NB + nl] = lb[(size_t)r * FEATURE_OUT + nb + nl];
    }
    __syncthreads();

    const int nl = tid >> 3;    // 0..31
    const int kq = tid & 7;     // 0..7, each covers 16 k

    f32x4_t bcol[4];
#pragma unroll
    for (int r4 = 0; r4 < 4; ++r4) {
        f32x4_t v;
#pragma unroll
        for (int j = 0; j < 4; ++j) v[j] = lbs[(r4 * 4 + j) * FW_NB + nl];
        bcol[r4] = v;
    }

    const f32x4_t* las4 = (const f32x4_t*)las;   // index k*4 + r4
    const float* wrow = w + (size_t)(nb + nl) * FEATURE_IN + kb + kq * 16;
    uint16_t* wfrow = wf + (size_t)(nb + nl) * FEATURE_IN + kb + kq * 16;

#pragma unroll
    for (int h = 0; h < 2; ++h) {          // two groups of 8 k
        float4 wv0 = ((const float4*)wrow)[h * 2 + 0];
        float4 wv1 = ((const float4*)wrow)[h * 2 + 1];
        float wfv[8] = {wv0.x, wv0.y, wv0.z, wv0.w, wv1.x, wv1.y, wv1.z, wv1.w};
        bf16x8_t o;
#pragma unroll
        for (int j = 0; j < 8; ++j) {
            const int k = kq * 16 + h * 8 + j;
            float s = 0.f;
#pragma unroll
            for (int rr = 0; rr < 4; ++rr) {
                const int r4 = (rr + kq) & 3;
                f32x4_t av = las4[k * 4 + r4];
                f32x4_t bv = bcol[r4];
                s += av[0] * bv[0] + av[1] * bv[1] + av[2] * bv[2] + av[3] * bv[3];
            }
            o[j] = (__bf16)(wfv[j] + 2.f * s);
        }
        ((bf16x8_t*)wfrow)[h] = o;
    }
}

// ========= GEMM: faithful m201-style 8-phase, BK=64, 2 bufs, 2 barriers/phase =======
// C[M,N] = Xb * Wf^T + bias.  8 waves (2M x 4N), per-wave out 128x64.
// 2 bufs x 64KB; even K-tiles -> buf0, odd -> buf1.  Half-tile = [128 rows][64 k],
// rows 128 B, slot permutation slot=(chunk+(row&7))&7 -> uniform 8 lanes/bank
// (conflict-free); staging stays LINEAR, source global addr inverse-permuted.
// Phase (x8 per tile-pair): {4 A-reads (+8 B-reads at ph1/ph5) | stage <=1 HT |
// schedb | BAR | lgkmcnt(0)+schedb | prio1 16 MFMA prio0 | [vmcnt(4) at ph4/ph8] |
// BAR}.  The second barrier fences reads-drained before any wave's next-phase gll
// can overwrite the HT (WAR-safe stage-after-read).
// Stage table (iter i, T0=2i,T1=2i+1 resident; ptrs at base k=i*128):
//   ph1: b1.Am0+Am1 <- T1 (+64)    ph2: b0.Bn0 <- T2 (+128)   ph3: b0.Bn1 (+128)
//   ph4: vmcnt(4)                  ph5: b0.Am0 <- T2 (+128)   ph6: b0.Am1 (+128)
//   ph7: b1.Bn0 <- T3 (+192)       ph8: b1.Bn1 (+192); vmcnt(4)
// Per-wave vmcnt ledger (2 loads/HT; 4 at ph1): entering iter = 4 outstanding
// {pPh7,pPh8}; @ph4: 12 -> keep 4 = {ph2,ph3}: retires T1's Am+Bn before ph5 reads
// buf1.  @ph8: 12 -> keep 4 = {ph7,ph8}: retires T2's 4 HTs before next ph1.
#define BM 256
#define BN 256
#define NPAIR 32               // 64 K-tiles of 64, in pairs

#define AHT(b, h) ((b) * 65536 + (h) * 16384)
#define BHT(b, h) ((b) * 65536 + 32768 + (h) * 16384)

#define READ_A(BF, QD) do { _Pragma("unroll")                                            \
    for (int _m = 0; _m < 2; ++_m) { _Pragma("unroll")                                   \
        for (int _s = 0; _s < 2; ++_s)                                                   \
            fa[_m][_s] = *(const bf16x8_t*)(lds + AHT(BF, waveM) +                       \
                ((QD) * 2 + _m) * 2048 + aRow + ((_s) ? cs1 : cs0)); } } while (0)

#define READ_B(BF) do { _Pragma("unroll")                                                \
    for (int _n = 0; _n < 4; ++_n) { _Pragma("unroll")                                   \
        for (int _s = 0; _s < 2; ++_s)                                                   \
            fb[_n][_s] = *(const bf16x8_t*)(lds + BHT(BF, nHalf) +                       \
                _n * 2048 + bRow + ((_s) ? cs1 : cs0)); } } while (0)

#define MFMA16(QD) do { _Pragma("unroll")                                                \
    for (int _s = 0; _s < 2; ++_s) { _Pragma("unroll")                                   \
        for (int _m = 0; _m < 2; ++_m) { _Pragma("unroll")                               \
            for (int _n = 0; _n < 4; ++_n)                                               \
                acc[(QD) * 2 + _m][_n] = __builtin_amdgcn_mfma_f32_16x16x32_bf16(        \
                    fa[_m][_s], fb[_n][_s], acc[(QD) * 2 + _m][_n], 0, 0, 0); } } } while (0)

#define GLL(SRC, DST)                                                                    \
    __builtin_amdgcn_global_load_lds(                                                    \
        (const __attribute__((address_space(1))) void*)(SRC),                            \
        (__attribute__((address_space(3))) void*)(DST), 16, 0, 0)

#define SA(BF, H, KO) do {                                                               \
    GLL(((H) ? pA1 : pA0) + (KO),  lds + AHT(BF, H) + wv * 1024);                        \
    GLL(((H) ? pA1b : pA0b) + (KO), lds + AHT(BF, H) + 8192 + wv * 1024); } while (0)
#define SB(BF, H, KO) do {                                                               \
    GLL(((H) ? pB1 : pB0) + (KO),  lds + BHT(BF, H) + wv * 1024);                        \
    GLL(((H) ? pB1b : pB0b) + (KO), lds + BHT(BF, H) + 8192 + wv * 1024); } while (0)

#define PBAR() __builtin_amdgcn_s_barrier()
#define PRIO1 __builtin_amdgcn_s_setprio(1)
#define PRIO0 __builtin_amdgcn_s_setprio(0)
#define VMCNT(n) asm volatile("s_waitcnt vmcnt(" #n ")" ::: "memory")
#define LGKM0() asm volatile("s_waitcnt lgkmcnt(0)" ::: "memory")
#define SCHEDB() __builtin_amdgcn_sched_barrier(0)

// phase core after reads+stage are issued
#define PH_TAIL(QD)                                                                      \
    SCHEDB();                                                                            \
    PBAR();                                                                              \
    LGKM0(); SCHEDB();                                                                   \
    PRIO1; MFMA16(QD); PRIO0;

__global__ __launch_bounds__(512, 2) void gemm8p(const uint16_t* __restrict__ Au,
                                                 const uint16_t* __restrict__ Bu,
                                                 const float* __restrict__ bias,
                                                 float* __restrict__ C,
                                                 int M, int N, int K) {
    __shared__ __align__(16) char lds[131072];   // 2 bufs x (Am0|Am1|Bn0|Bn1) x 16KB

    const __bf16* A = (const __bf16*)Au;
    const __bf16* B = (const __bf16*)Bu;

    const int tid  = threadIdx.x;
    const int wv   = tid >> 6;          // 0..7
    const int lane = tid & 63;
    const int waveM = wv >> 2;          // 0..1
    const int waveN = wv & 3;           // 0..3
    const int nHalf = waveN >> 1;       // 0..1
    const int l15 = lane & 15;
    const int q   = lane >> 4;          // 0..3

    // T1: bijective XCD-chunk swizzle (nwg=512, 512%8==0)
    const int nbx = N / BN;
    const int nwg = nbx * (M / BM);
    const int bidlin = blockIdx.y * nbx + blockIdx.x;
    const int swz = (bidlin & 7) * (nwg >> 3) + (bidlin >> 3);
    const int by = swz / nbx;
    const int bx = swz - by * nbx;
    const int m0 = by * BM;
    const int n0 = bx * BN;

    // staging sources: thread t covers HT row r=t>>3 (gll0) / 64+r (gll1) at slot
    // t&7; stored chunk c = ((t&7) - (r&7)) & 7 -> src k-offset c*8
    const int srow = tid >> 3;                       // 0..63
    const int sc   = ((tid & 7) - (srow & 7)) & 7;
    const __bf16* pA0  = A + (size_t)(m0 + srow) * K + sc * 8;        // Am0 rows 0..63
    const __bf16* pA0b = pA0 + (size_t)64 * K;                        // Am0 rows 64..127
    const __bf16* pA1  = A + (size_t)(m0 + 128 + srow) * K + sc * 8;  // Am1
    const __bf16* pA1b = pA1 + (size_t)64 * K;
    const __bf16* pB0  = B + (size_t)(n0 + srow) * K + sc * 8;        // Bn0
    const __bf16* pB0b = pB0 + (size_t)64 * K;
    const __bf16* pB1  = B + (size_t)(n0 + 128 + srow) * K + sc * 8;  // Bn1
    const __bf16* pB1b = pB1 + (size_t)64 * K;

    // fragment read offsets: row = (frag*16 + l15), byte = row*128 + slot*16,
    // slot = (ks*4 + q + (row&7)) & 7; row&7 == l15&7 (frag*16 = 0 mod 8)
    const int aRow = l15 * 128;
    const int bRow = ((waveN & 1) * 64 + l15) * 128;
    const int s0 = (q + (l15 & 7)) & 7;
    const int cs0 = s0 * 16;
    const int cs1 = (s0 ^ 4) * 16;     // (slot+4)&7 == slot^4

    f32x4_t acc[8][4];
#pragma unroll
    for (int mi = 0; mi < 8; ++mi)
#pragma unroll
        for (int ni = 0; ni < 4; ++ni)
            acc[mi][ni] = (f32x4_t)0.f;

    bf16x8_t fa[2][2], fb[4][2];

    // ---- prologue: buf0 <- T0 (4 HT, 8 gll); b1.Bn0/Bn1 <- T1 (4 gll) ----
    SA(0, 0, 0); SA(0, 1, 0); SB(0, 0, 0); SB(0, 1, 0);
    SB(1, 0, 64); SB(1, 1, 64);
    VMCNT(4);                 // retire T0's 8; keep T1.Bn x4 (steady-state entry)
    PBAR();

    // ---- main: 31 iterations = tile pairs 0..30 (tiles 0..61), staging to T=63 ----
#pragma unroll 1
    for (int i = 0; i < 31; ++i) {
        // ph1: T0-Q0, read B(T0); stage b1.Am0+Am1 <- T1
        READ_A(0, 0); READ_B(0);
        SA(1, 0, 64); SA(1, 1, 64);
        PH_TAIL(0);
        PBAR();
        // ph2: T0-Q1; stage b0.Bn0 <- T2
        READ_A(0, 1);
        SB(0, 0, 128);
        PH_TAIL(1);
        PBAR();
        // ph3: T0-Q2; stage b0.Bn1 <- T2
        READ_A(0, 2);
        SB(0, 1, 128);
        PH_TAIL(2);
        PBAR();
        // ph4: T0-Q3; vmcnt(4) gates buf1 (T1 fully landed)
        READ_A(0, 3);
        PH_TAIL(3);
        VMCNT(4);
        PBAR();
        // ph5: T1-Q0, read B(T1); stage b0.Am0 <- T2
        READ_A(1, 0); READ_B(1);
        SA(0, 0, 128);
        PH_TAIL(0);
        PBAR();
        // ph6: T1-Q1; stage b0.Am1 <- T2
        READ_A(1, 1);
        SA(0, 1, 128);
        PH_TAIL(1);
        PBAR();
        // ph7: T1-Q2; stage b1.Bn0 <- T3
        READ_A(1, 2);
        SB(1, 0, 192);
        PH_TAIL(2);
        PBAR();
        // ph8: T1-Q3; stage b1.Bn1 <- T3; vmcnt(4) gates buf0 (T2 landed)
        READ_A(1, 3);
        SB(1, 1, 192);
        PH_TAIL(3);
        VMCNT(4);
        PBAR();
        // advance base k by 2 tiles
        pA0 += 128; pA0b += 128; pA1 += 128; pA1b += 128;
        pB0 += 128; pB0b += 128; pB1 += 128; pB1b += 128;
    }

    // ---- epilogue pair (tiles 62,63); ptr base k = 62*64; only ph1 stages ----
    READ_A(0, 0); READ_B(0);
    SA(1, 0, 64); SA(1, 1, 64);       // b1.Am <- T63
    PH_TAIL(0);
    PBAR();
    READ_A(0, 1);
    PH_TAIL(1);
    PBAR();
    READ_A(0, 2);
    PH_TAIL(2);
    PBAR();
    READ_A(0, 3);
    PH_TAIL(3);
    VMCNT(0);                          // T63 fully landed
    PBAR();
    READ_A(1, 0); READ_B(1);
    PH_TAIL(0);
    PBAR();
    READ_A(1, 1);
    PH_TAIL(1);
    PBAR();
    READ_A(1, 2);
    PH_TAIL(2);
    PBAR();
    READ_A(1, 3);
    SCHEDB();
    LGKM0(); SCHEDB();
    PRIO1; MFMA16(3); PRIO0;

    // ---- C write: D layout col=lane&15, row=q*4+j ----
#pragma unroll
    for (int ni = 0; ni < 4; ++ni) {
        const int col = n0 + waveN * 64 + ni * 16 + l15;
        const float bv = bias[col];
#pragma unroll
        for (int mi = 0; mi < 8; ++mi) {
            const int row = m0 + waveM * 128 + mi * 16 + q * 4;
            float* op = C + (size_t)row * N + col;
#pragma unroll
            for (int j = 0; j < 4; ++j)
                op[(size_t)j * N] = acc[mi][ni][j] + bv;
        }
    }
}

extern "C" void kernel_launch(void* const* d_in, const int* in_sizes, int n_in,
                              void* d_out, int out_size, void* d_ws, size_t ws_size,
                              hipStream_t stream) {
    const float* x  = (const float*)d_in[0];   // [4,2048,4096]
    const float* w  = (const float*)d_in[1];   // [4096,4096]  (out,in)
    const float* b  = (const float*)d_in[2];   // [4096]
    const float* la = (const float*)d_in[3];   // [4096,16]
    const float* lb = (const float*)d_in[4];   // [16,4096]
    float* out = (float*)d_out;

    const int M = in_sizes[0] / FEATURE_IN;    // 8192
    const int K = FEATURE_IN;
    const int N = FEATURE_OUT;

    uint16_t* xb = (uint16_t*)d_ws;                                  // M*K bf16 = 64 MiB
    uint16_t* wf = (uint16_t*)((char*)d_ws + (size_t)M * K * 2);     // N*K bf16 = 32 MiB

    // 1) prep: x->bf16 + LoRA-folded W->bf16 (single dispatch, both roles)
    prep_all<<<NFUSE + NCVTB, 256, 0, stream>>>(x, xb, w, la, lb, wf);

    // 2) GEMM + bias: 8-phase BK=64 two-buffer schedule (m201-faithful port)
    {
        dim3 grid(N / BN, M / BM);   // (16, 32)
        gemm8p<<<grid, 512, 0, stream>>>(xb, wf, b, out, M, N, K);
    }
}